// Round 3
// baseline (542.977 us; speedup 1.0000x reference)
//
#include <hip/hip_runtime.h>
#include <stdint.h>

typedef __attribute__((ext_vector_type(8))) short short8;
typedef __attribute__((ext_vector_type(4))) float f32x4;

#define N_IMG 32
#define C_IN  256
#define HH    64
#define WW    64
#define O_OUT 256
#define HP    66
#define WP    66

#define QX_ELEMS (N_IMG*HP*WP*C_IN)      // 35,684,352
#define QX_BYTES ((size_t)QX_ELEMS*2)    // 71,368,704
#define QW_ELEMS (9*O_OUT*C_IN)          // 589,824

// ---------- quantization helpers (match jnp reference bit-for-bit) ----------

// nearest E2M1 magnitude; ties round up (jnp.digitize right=False: a==mid -> upper)
__device__ __forceinline__ float e2m1_mag(float a) {
    return a < 0.25f ? 0.0f
         : a < 0.75f ? 0.5f
         : a < 1.25f ? 1.0f
         : a < 1.75f ? 1.5f
         : a < 2.5f  ? 2.0f
         : a < 3.5f  ? 3.0f
         : a < 5.0f  ? 4.0f : 6.0f;
}

// scale = 2^ceil(log2(max(amax,1e-30)/6)), or 1.0 if amax==0; also exact 1/scale.
__device__ __forceinline__ void blk_scale2(float amax, float& s, float& inv) {
    float ac = fmaxf(amax, 1e-30f);
    int e;
    float m = frexpf(ac, &e);
    int ex = (m > 0.75f) ? (e - 2) : (e - 3);
    if (amax > 0.0f) { s = ldexpf(1.0f, ex); inv = ldexpf(1.0f, -ex); }
    else             { s = 1.0f; inv = 1.0f; }
}

// E2M1-grid * pow2 -> 1 mantissa bit -> exact in bf16 (truncate == round)
__device__ __forceinline__ unsigned short to_bf16_bits(float v) {
    union { float f; unsigned int u; } cv; cv.f = v;
    return (unsigned short)(cv.u >> 16);
}

// ---------- halo zero: only the 4.3 MB border of qx ----------
__global__ __launch_bounds__(256) void halo_zero_kernel(unsigned short* __restrict__ qx) {
    int id = blockIdx.x * 256 + threadIdx.x;
    size_t off;
    if (id < 135168) {
        int n = id / 4224, r = id % 4224;
        int h = (r / 2112) * 65;
        int k = r % 2112;
        off = (((size_t)(n*HP + h)) * WP) * C_IN + (size_t)k * 8;
    } else {
        int j = id - 135168;
        int n = j >> 12, r = j & 4095;
        int h = 1 + (r >> 6);
        int w = ((r >> 5) & 1) * 65;
        int k = r & 31;
        off = (((size_t)(n*HP + h)) * WP + w) * C_IN + (size_t)k * 8;
    }
    uint4 z; z.x = z.y = z.z = z.w = 0u;
    *(uint4*)(qx + off) = z;
}

// ---------- x: fp32 NCHW -> exact-bf16 NHWC(+halo) ----------
__global__ __launch_bounds__(256) void quant_x_kernel(const float* __restrict__ x,
                                                      unsigned short* __restrict__ qx) {
    __shared__ float xf[64][65];
    __shared__ float sarr[4][65];
    __shared__ float iarr[4][65];

    const int bid = blockIdx.x;
    const int n  = bid >> 8;
    const int h  = (bid >> 2) & 63;
    const int cb = bid & 3;
    const int t  = threadIdx.x;

    {
        const int rb = t >> 4;
        const int w4 = (t & 15) * 4;
        const float* src = x + (((size_t)(n*C_IN + cb*64)) * HH + h) * WW;
#pragma unroll
        for (int it = 0; it < 4; ++it) {
            int r = it * 16 + rb;
            float4 g = *(const float4*)(src + (size_t)r * (HH*WW) + w4);
            xf[r][w4+0] = g.x; xf[r][w4+1] = g.y; xf[r][w4+2] = g.z; xf[r][w4+3] = g.w;
        }
    }
    __syncthreads();

    {
        const int c = t >> 2, wb = t & 3;
        float amax = 0.f;
#pragma unroll
        for (int j = 0; j < 16; ++j) amax = fmaxf(amax, fabsf(xf[c][wb*16 + j]));
        float s, inv;
        blk_scale2(amax, s, inv);
        sarr[wb][c] = s;
        iarr[wb][c] = inv;
    }
    __syncthreads();

    {
        const int w = t >> 2, cg = (t & 3) * 16, wb = w >> 4;
        unsigned short outv[16];
#pragma unroll
        for (int i = 0; i < 16; ++i) {
            int c = cg + i;
            float v = xf[c][w];
            float q = copysignf(e2m1_mag(fabsf(v) * iarr[wb][c]) * sarr[wb][c], v);
            outv[i] = to_bf16_bits(q);
        }
        unsigned short* dst = qx + (((size_t)(n*HP + h + 1)) * WP + (w + 1)) * C_IN + cb*64 + cg;
        *(uint4*)(dst)     = *(const uint4*)&outv[0];
        *(uint4*)(dst + 8) = *(const uint4*)&outv[8];
    }
}

// ---------- w: fp32 OIHW -> exact-bf16 [O][9][C] (row = 2304 contiguous) ----------
__global__ __launch_bounds__(256) void quant_w_kernel(const float* __restrict__ w,
                                                      unsigned short* __restrict__ qw) {
    __shared__ unsigned short lq[2304];   // one o-row, (ci*9 + p) order
    const int o = blockIdx.x;
    const int t = threadIdx.x;
    const float* src = w + (size_t)o * 2304;
    if (t < 144) {
        float v[16];
#pragma unroll
        for (int j = 0; j < 4; ++j) {
            float4 f = ((const float4*)(src + t*16))[j];
            v[j*4+0]=f.x; v[j*4+1]=f.y; v[j*4+2]=f.z; v[j*4+3]=f.w;
        }
        float amax = 0.f;
#pragma unroll
        for (int j = 0; j < 16; ++j) amax = fmaxf(amax, fabsf(v[j]));
        float s, inv;
        blk_scale2(amax, s, inv);
#pragma unroll
        for (int j = 0; j < 16; ++j)
            lq[t*16 + j] = to_bf16_bits(copysignf(e2m1_mag(fabsf(v[j]) * inv) * s, v[j]));
    }
    __syncthreads();
    // thread t = ci; write [o][p][ci]: per p, 256 lanes x 2B = contiguous 512B
#pragma unroll
    for (int p = 0; p < 9; ++p)
        qw[(size_t)o*2304 + p*C_IN + t] = lq[t*9 + p];
}

// ---------- conv: implicit GEMM; A=weights direct L2->VGPR, B=pixels via LDS ----------
__device__ __forceinline__ void gld16(void* lds, const void* g) {
    __builtin_amdgcn_global_load_lds(
        (const __attribute__((address_space(1))) unsigned int*)g,
        (__attribute__((address_space(3))) unsigned int*)lds,
        16, 0, 0);
}

__global__ __launch_bounds__(256) void conv_kernel(const unsigned short* __restrict__ qw,
                                                   const unsigned short* __restrict__ qx,
                                                   float* __restrict__ out) {
    __shared__ unsigned short Xb[2][128][32];   // double-buffered B tile, 16 KB

    const int tid  = threadIdx.x;
    const int wave = tid >> 6;
    const int lane = tid & 63;
    const int lo16 = lane & 15;
    const int quad = lane >> 4;

    // XCD/L2 swizzle (proven: FETCH 390->54 MB): id&7 = image group; o-tile pair adjacent
    const int id  = blockIdx.x;              // 0..2047
    const int g   = id >> 3;
    const int n   = ((g >> 6) << 3) | (id & 7);
    const int j_  = g & 63;
    const int o0  = (j_ & 1) * 128;
    const int hw0 = (j_ >> 1) * 128;
    const int h0  = hw0 >> 6;

    // ---- B staging geometry (gld16 forces LDS slot = base + lane*16B) ----
    // XOR swizzle: physical chunk (lane&3) holds logical k-chunk (lane&3)^sw(row),
    // sw(row) = (row>>1)&3. Reads then hit all 32 banks per 8 consecutive lanes.
    const int r0 = wave*32 + (lane >> 2);
    const int r1 = r0 + 16;
    const int cl = (lane & 3) ^ ((lane >> 3) & 3);
    const int co = cl * 8;                   // shorts

    const unsigned short* xb0 = qx + (((size_t)(n*HP + h0 + (r0 >> 6) + 1))*WP + (r0 & 63) + 1)*C_IN + co;
    const unsigned short* xb1 = qx + (((size_t)(n*HP + h0 + (r1 >> 6) + 1))*WP + (r1 & 63) + 1)*C_IN + co;

    unsigned short* ldsB0[2] = { &Xb[0][wave*32][0],      &Xb[1][wave*32][0] };
    unsigned short* ldsB1[2] = { &Xb[0][wave*32 + 16][0], &Xb[1][wave*32 + 16][0] };

    // ---- A direct: 4 o-rows per wave, qw row = 2304 shorts, per-stage offset +32 ----
    const int wmo = (wave & 1) * 64;
    const int wnp = (wave >> 1) * 64;
    const unsigned short* ap[4];
#pragma unroll
    for (int i = 0; i < 4; ++i)
        ap[i] = qw + (size_t)(o0 + wmo + i*16 + lo16) * 2304 + quad*8;

    const int pq8 = (quad ^ ((lo16 >> 1) & 3)) * 8;   // physical chunk for B reads

    f32x4 acc[4][4];
#pragma unroll
    for (int i = 0; i < 4; ++i)
#pragma unroll
        for (int j = 0; j < 4; ++j)
            acc[i][j] = (f32x4){0.f, 0.f, 0.f, 0.f};

    short8 areg[2][4];

    // prologue: stage chunk 0 (p=0 -> xoff = (-66-1)*256 = -17152; in-bounds: base >= 17152)
    const int XO0 = -17152;
    gld16(ldsB0[0], xb0 + XO0);
    gld16(ldsB1[0], xb1 + XO0);
#pragma unroll
    for (int i = 0; i < 4; ++i) areg[0][i] = *(const short8*)(ap[i]);

    int xo = XO0;
    for (int p = 0; p < 9; ++p) {
        // xoff deltas between kpos: {1,1,64,1,1,64,1,1} * 256 shorts
        const int xo_n = xo + (((p == 2) | (p == 5)) ? 64*256 : 256);
        const int pb   = p * 256;            // qw short offset base for this p
#pragma unroll
        for (int cc = 0; cc < 8; ++cc) {
            const int cur = cc & 1;          // (p*8+cc)&1 == cc&1
            const int nxt = cur ^ 1;
            // one barrier per chunk; compiler's vmcnt(0) drain covers loads issued
            // a full chunk earlier (hidden). Also makes Xb[nxt] safe to overwrite.
            __syncthreads();
            // stage chunk it+1 into the other buffer / register set
            if (cc < 7) {
                const int bo = xo + (cc + 1) * 32;
                gld16(ldsB0[nxt], xb0 + bo);
                gld16(ldsB1[nxt], xb1 + bo);
                const int ao = pb + (cc + 1) * 32;
#pragma unroll
                for (int i = 0; i < 4; ++i) areg[nxt][i] = *(const short8*)(ap[i] + ao);
            } else if (p < 8) {
                gld16(ldsB0[nxt], xb0 + xo_n);
                gld16(ldsB1[nxt], xb1 + xo_n);
                const int ao = pb + 256;
#pragma unroll
                for (int i = 0; i < 4; ++i) areg[nxt][i] = *(const short8*)(ap[i] + ao);
            }
            // compute on cur
            short8 bf_[4];
#pragma unroll
            for (int j = 0; j < 4; ++j)
                bf_[j] = *(const short8*)&Xb[cur][wnp + j*16 + lo16][pq8];
#pragma unroll
            for (int i = 0; i < 4; ++i)
#pragma unroll
                for (int j = 0; j < 4; ++j)
                    acc[i][j] = __builtin_amdgcn_mfma_f32_16x16x32_bf16(
                        areg[cur][i], bf_[j], acc[i][j], 0, 0, 0);
        }
        xo = xo_n;
    }

    // epilogue: D col (lane&15) = pixel -> contiguous stores over pixels
#pragma unroll
    for (int i = 0; i < 4; ++i) {
#pragma unroll
        for (int j = 0; j < 4; ++j) {
            int o  = o0 + wmo + i*16 + quad*4;
            int pl = wnp + j*16 + lo16;
            size_t base = ((size_t)(n*O_OUT + o)) * (HH*WW) + hw0 + pl;
#pragma unroll
            for (int r = 0; r < 4; ++r)
                out[base + (size_t)r*(HH*WW)] = acc[i][j][r];
        }
    }
}

extern "C" void kernel_launch(void* const* d_in, const int* in_sizes, int n_in,
                              void* d_out, int out_size, void* d_ws, size_t ws_size,
                              hipStream_t stream) {
    const float* x = (const float*)d_in[0];
    const float* w = (const float*)d_in[1];
    float* out = (float*)d_out;

    unsigned short* qx = (unsigned short*)d_ws;                       // padded NHWC bf16
    unsigned short* qw = (unsigned short*)((char*)d_ws + QX_BYTES);   // [O][9][C] bf16

    halo_zero_kernel<<<dim3(1040), 256, 0, stream>>>(qx);
    quant_x_kernel<<<dim3(N_IMG*HH*4), 256, 0, stream>>>(x, qx);
    quant_w_kernel<<<dim3(O_OUT), 256, 0, stream>>>(w, qw);
    conv_kernel<<<dim3(2048), 256, 0, stream>>>(qw, qx, out);
}